// Round 7
// baseline (235.185 us; speedup 1.0000x reference)
//
#include <hip/hip_runtime.h>
#include <math.h>

#define NN 512
#define KP 64
#define NPANEL 8
#define NTHR 256
#define NBLK 256
#define TRUNITS (448 * 112)

// LDS float offsets (25728 floats = 100.5 KB -> 1 block/CU).
// Strides: 65 for scalar-read-by-row tiles (D,V), 68 for float4-aligned
// staged tiles (68%32=4 -> stride-4-row scalar reads land in distinct banks).
#define D_   0        // 64 x 65   diag block (state p)
#define V_   4160     // 64 x 65   V-state for substitution
#define B2_  8320     // 64 x 68   Cprev k0-rows tile
#define UB_  12672    // 64 x 68   Rprev k0-cols tile
#define SB_  17024    // 64 x 68   own-slice prev tile
#define H_   21376    // 64 x 68   evolve snapshot history
#define LDSN 25728

__device__ __forceinline__ float einit(const float* s, const float* dI, int i, int j) {
  float w = dI[i * NN + j] / (s[i * NN + j] + 1e-4f);
  if (i == j) w = 0.f;
  return expf(-10.f * w);
}

// Triangular evolve segment: pivots [M0,M1). H row m is snapshotted BEFORE
// pivot m's update; updates to rows a <= m feed nothing live downstream
// (H[a] already extracted; readlane multipliers for row a come from x[a]
// itself), so the inner loop starts at a=m+1. Bitwise-identical H.
template <int M0, int M1>
__device__ __forceinline__ void evolve_seg(float* lds, float (&x)[64], int tid) {
#pragma unroll
  for (int m = M0; m < M1; ++m) {
    const float xm = x[m];
    lds[H_ + m * 68 + tid] = xm;
#pragma unroll
    for (int a = m + 1; a < 64; ++a) {
      const int sa = __builtin_amdgcn_readlane(__float_as_int(x[a]), m);
      x[a] += __int_as_float(sa) * xm;
    }
  }
}

// Substitution partial GEMM for chunk cch (cols [16c,16c+16)): adds pivot
// contributions mp < 16c. Runs on 128 threads, tt2 in [0,128).
__device__ __forceinline__ void pgemm_chunk(float* lds, int cch, int tt2, int h) {
  const int mb = cch * 16;
  const int r = 32 * h + (tt2 & 31);
  const int g = tt2 >> 5;
  const int m0c = mb + 4 * g;
  const int vb = V_ + r * 65;
  float a0 = lds[vb + m0c + 0], a1 = lds[vb + m0c + 1];
  float a2 = lds[vb + m0c + 2], a3 = lds[vb + m0c + 3];
  for (int mp = 0; mp < mb; ++mp) {
    const float vr = lds[vb + mp];
    const float4 u4 = *(const float4*)&lds[H_ + mp * 68 + m0c];
    a0 += vr * u4.x; a1 += vr * u4.y; a2 += vr * u4.z; a3 += vr * u4.w;
  }
  lds[vb + m0c + 0] = a0; lds[vb + m0c + 1] = a1;
  lds[vb + m0c + 2] = a2; lds[vb + m0c + 3] = a3;
}

// Sequential 16x16 closure of chunk cch over this block's 32 V rows.
// t3 in [0,32).
__device__ __forceinline__ void micro_chunk(float* lds, int cch, int t3, int h) {
  const int mb = cch * 16;
  const int r = 32 * h + t3;
  const int vb = V_ + r * 65 + mb;
  float v[16];
#pragma unroll
  for (int u2 = 0; u2 < 16; ++u2) v[u2] = lds[vb + u2];
#pragma unroll
  for (int mp = 0; mp < 15; ++mp) {
    const float vmp = v[mp];
#pragma unroll
    for (int m2 = mp + 1; m2 < 16; ++m2)
      v[m2] += vmp * lds[H_ + (mb + mp) * 68 + (mb + m2)];
  }
#pragma unroll
  for (int u2 = 0; u2 < 16; ++u2) lds[vb + u2] = v[u2];
}

// Phase p (one launch per phase; inter-launch barrier = phase sync):
//  blocks 0..31  : panel blocks. Prefetch E reads (diag+slice) to regs,
//    stage prev C/R tiles, diag GEMM, then an 8-slot pipeline exploiting
//    the TRIANGULAR evolve cost profile: long early segments overlap the
//    slice GEMM and early substitution; short late segments overlap the
//    heavy pgemm chunks. Dependency ladder (H rows / final V cols) has
//    one-slot slack at every edge:
//      s1 ev[0,16)  || slice GEMM      s5 ev[40,48) || pgemm2
//      s2 ev[16,24) || micro0          s6 ev[48,56) || micro2
//      s3 ev[24,32) || pgemm1          s7 ev[56,64) || pgemm3
//      s4 ev[32,40) || micro1          s8 micro3
//  blocks 32..255: trailing rank-64 update of complement(cross(p)) (p>0),
//    or E init there (p==0).
// Diag block (p,p) never written in-phase; diag b misses exactly
// C_{b-1}R_{b-1}, fixed in k_loss (which also adds C_7R_7).
__global__ __launch_bounds__(NTHR) void fw_phase(
    const float* __restrict__ s, const float* __restrict__ dI,
    float* __restrict__ E, float* __restrict__ Cs, float* __restrict__ Rs,
    float* __restrict__ out, int p) {
  __shared__ __align__(16) float lds[LDSN];
  const int blk = blockIdx.x, tid = threadIdx.x;
  const int k0 = p * KP;

  if (blk >= 32) {
    // ================= trailing blocks =================
    const int gt = (blk - 32) * NTHR + tid;
    if (p == 0) {
      if (blk == 32 && tid == 0) out[0] = 0.f;   // zero loss accumulator
      if (gt < TRUNITS) {
        const int ii = gt / 112;
        const int jj = gt - ii * 112;
        const int i = ii + KP;
        const int j = (jj + 16) << 2;
        const int idx = i * NN + j;
        const float4 sv = *(const float4*)(s + idx);
        const float4 dv = *(const float4*)(dI + idx);
        float w0 = dv.x / (sv.x + 1e-4f); if (i == j + 0) w0 = 0.f;
        float w1 = dv.y / (sv.y + 1e-4f); if (i == j + 1) w1 = 0.f;
        float w2 = dv.z / (sv.z + 1e-4f); if (i == j + 2) w2 = 0.f;
        float w3 = dv.w / (sv.w + 1e-4f); if (i == j + 3) w3 = 0.f;
        *(float4*)(E + idx) = make_float4(expf(-10.f * w0), expf(-10.f * w1),
                                          expf(-10.f * w2), expf(-10.f * w3));
      }
    } else if (gt < TRUNITS) {
      const int ii = gt / 112;
      const int jj = gt - ii * 112;
      const int i = (ii < k0) ? ii : ii + KP;
      const int j = ((jj < (p << 4)) ? jj : jj + 16) << 2;
      const int idx = i * NN + j;
      const float* Cprev = Cs + (size_t)(p - 1) * (NN * KP);
      const float* Rprev = Rs + (size_t)(p - 1) * (KP * NN);
      float4 acc = *(const float4*)(E + idx);
      const float4* crow4 = (const float4*)(Cprev + (size_t)i * KP);
      const float* rcol = Rprev + j;
#pragma unroll 4
      for (int r4 = 0; r4 < 16; ++r4) {
        const float4 cv4 = crow4[r4];
        const float* rb = rcol + (size_t)(r4 * 4) * NN;
        float4 rv;
        rv = *(const float4*)(rb);
        acc.x += cv4.x * rv.x; acc.y += cv4.x * rv.y;
        acc.z += cv4.x * rv.z; acc.w += cv4.x * rv.w;
        rv = *(const float4*)(rb + NN);
        acc.x += cv4.y * rv.x; acc.y += cv4.y * rv.y;
        acc.z += cv4.y * rv.z; acc.w += cv4.y * rv.w;
        rv = *(const float4*)(rb + 2 * NN);
        acc.x += cv4.z * rv.x; acc.y += cv4.z * rv.y;
        acc.z += cv4.z * rv.z; acc.w += cv4.z * rv.w;
        rv = *(const float4*)(rb + 3 * NN);
        acc.x += cv4.w * rv.x; acc.y += cv4.w * rv.y;
        acc.z += cv4.w * rv.z; acc.w += cv4.w * rv.w;
      }
      *(float4*)(E + idx) = acc;
    }
    return;
  }

  // ================= panel blocks =================
  const bool isC = (blk < 16);
  const int sb = (blk >> 1) & 7;
  const int h = blk & 1;                 // half: rows/cols [32h, 32h+32)
  const int sOff = sb * KP;
  const bool haveSl = (sb != p);
  const float* Cprev = Cs + (size_t)(p - 1) * (NN * KP);
  const float* Rprev = Rs + (size_t)(p - 1) * (KP * NN);

  // prefetched E fragments (loaded in p>0 path before the staging barrier;
  // consumed by diag GEMM / slice GEMM). Race-free: diag(p) is not written
  // in-phase by anyone; the slice region is written only by THIS block.
  float4 eS[4];

  if (p == 0) {
    // direct init of diag + own slice; write E (blk0 owns diag region)
    for (int e = tid; e < 4096; e += NTHR) {
      const int a = e >> 6, b = e & 63;
      const float v = einit(s, dI, a, b);
      lds[D_ + a * 65 + b] = v;
      if (blk == 0) E[a * NN + b] = v;
    }
    if (haveSl) {
      if (isC) {
        for (int e = tid; e < 2048; e += NTHR) {
          const int a = 32 * h + (e >> 6), b = e & 63;
          const float v = einit(s, dI, sOff + a, b);
          lds[V_ + a * 65 + b] = v;
          E[(sOff + a) * NN + b] = v;
        }
      } else {
        for (int e = tid; e < 2048; e += NTHR) {
          const int m = e >> 5, j = 32 * h + (e & 31);
          const float v = einit(s, dI, m, sOff + j);
          lds[V_ + j * 65 + m] = v;
          E[m * NN + (sOff + j)] = v;
        }
      }
    }
  } else {
    // -------- prefetch E reads (overlap with staging latency) --------
    float4 eD[4];
    {
      const int r0 = (tid >> 4) << 2, m0 = (tid & 15) << 2;
#pragma unroll
      for (int i2 = 0; i2 < 4; ++i2)
        eD[i2] = *(const float4*)(E + (size_t)(k0 + r0 + i2) * NN + (k0 + m0));
    }
    if (haveSl && tid >= 64 && tid < 192) {
      const int tt = tid - 64;
      if (isC) {
        const int r0 = 32 * h + ((tt >> 4) << 2);
        const int m0 = (tt & 15) << 2;
#pragma unroll
        for (int i2 = 0; i2 < 4; ++i2)
          eS[i2] = *(const float4*)(E + (size_t)(sOff + r0 + i2) * NN + (k0 + m0));
      } else {
        const int r0 = (tt & 15) << 2;
        const int c0 = 32 * h + ((tt >> 4) << 2);
#pragma unroll
        for (int i2 = 0; i2 < 4; ++i2)
          eS[i2] = *(const float4*)(E + (size_t)(k0 + r0 + i2) * NN + (sOff + c0));
      }
    }
    // -------- stage tiles (float4, stride-68) --------
#pragma unroll
    for (int k = 0; k < 4; ++k) {
      const int e4 = tid + k * NTHR;
      const int a = e4 >> 4, b4 = (e4 & 15) << 2;
      *(float4*)&lds[B2_ + a * 68 + b4] =
          *(const float4*)(Cprev + (size_t)(k0 + a) * KP + b4);
      *(float4*)&lds[UB_ + a * 68 + b4] =
          *(const float4*)(Rprev + (size_t)a * NN + (k0 + b4));
      if (haveSl) {
        if (isC)
          *(float4*)&lds[SB_ + a * 68 + b4] =
              *(const float4*)(Cprev + (size_t)(sOff + a) * KP + b4);
        else
          *(float4*)&lds[SB_ + a * 68 + b4] =
              *(const float4*)(Rprev + (size_t)a * NN + (sOff + b4));
      }
    }
    __syncthreads();
    // -------- diag GEMM: D = E[diag] + Ck0 * Rk0 (state p) --------
    {
      const int r0 = (tid >> 4) << 2, m0 = (tid & 15) << 2;
      float acc[4][4];
#pragma unroll
      for (int i2 = 0; i2 < 4; ++i2) {
        acc[i2][0] = eD[i2].x; acc[i2][1] = eD[i2].y;
        acc[i2][2] = eD[i2].z; acc[i2][3] = eD[i2].w;
      }
      for (int rr = 0; rr < KP; rr += 4) {
        float4 av[4];
#pragma unroll
        for (int i2 = 0; i2 < 4; ++i2)
          av[i2] = *(const float4*)&lds[B2_ + (r0 + i2) * 68 + rr];
#pragma unroll
        for (int k = 0; k < 4; ++k) {
          const float4 b4 = *(const float4*)&lds[UB_ + (rr + k) * 68 + m0];
#pragma unroll
          for (int i2 = 0; i2 < 4; ++i2) {
            const float a = (k == 0) ? av[i2].x : (k == 1) ? av[i2].y
                          : (k == 2) ? av[i2].z : av[i2].w;
            acc[i2][0] += a * b4.x; acc[i2][1] += a * b4.y;
            acc[i2][2] += a * b4.z; acc[i2][3] += a * b4.w;
          }
        }
      }
#pragma unroll
      for (int i2 = 0; i2 < 4; ++i2)
#pragma unroll
        for (int j2 = 0; j2 < 4; ++j2)
          lds[D_ + (r0 + i2) * 65 + (m0 + j2)] = acc[i2][j2];
    }
  }
  __syncthreads();

  // ======== 8-slot pipeline: wave0 evolve (triangular) || waves1-3 ========
  float x[64];
  // ---- s1: evolve[0,16) || slice GEMM / diag-slice copy ----
  if (tid < 64) {
    if (isC) {
#pragma unroll
      for (int a = 0; a < 64; ++a) x[a] = lds[D_ + a * 65 + tid];
    } else {
#pragma unroll
      for (int a = 0; a < 64; ++a) x[a] = lds[D_ + tid * 65 + a];
    }
    evolve_seg<0, 16>(lds, x, tid);
  } else if (tid < 192) {
    const int tt = tid - 64;
    if (haveSl && p > 0) {
      // slice GEMM: V = E[slice] + prev rank-64; write corrected E back
      float acc[4][4];
      if (isC) {
        const int r0 = 32 * h + ((tt >> 4) << 2);
        const int m0 = (tt & 15) << 2;
#pragma unroll
        for (int i2 = 0; i2 < 4; ++i2) {
          acc[i2][0] = eS[i2].x; acc[i2][1] = eS[i2].y;
          acc[i2][2] = eS[i2].z; acc[i2][3] = eS[i2].w;
        }
        for (int rr = 0; rr < KP; rr += 4) {
          float4 av[4];
#pragma unroll
          for (int i2 = 0; i2 < 4; ++i2)
            av[i2] = *(const float4*)&lds[SB_ + (r0 + i2) * 68 + rr];
#pragma unroll
          for (int k = 0; k < 4; ++k) {
            const float4 b4 = *(const float4*)&lds[UB_ + (rr + k) * 68 + m0];
#pragma unroll
            for (int i2 = 0; i2 < 4; ++i2) {
              const float a = (k == 0) ? av[i2].x : (k == 1) ? av[i2].y
                            : (k == 2) ? av[i2].z : av[i2].w;
              acc[i2][0] += a * b4.x; acc[i2][1] += a * b4.y;
              acc[i2][2] += a * b4.z; acc[i2][3] += a * b4.w;
            }
          }
        }
#pragma unroll
        for (int i2 = 0; i2 < 4; ++i2) {
          *(float4*)(E + (size_t)(sOff + r0 + i2) * NN + (k0 + m0)) =
              make_float4(acc[i2][0], acc[i2][1], acc[i2][2], acc[i2][3]);
#pragma unroll
          for (int j2 = 0; j2 < 4; ++j2)
            lds[V_ + (r0 + i2) * 65 + (m0 + j2)] = acc[i2][j2];
        }
      } else {
        const int r0 = (tt & 15) << 2;              // m rows k0+r0..
        const int c0 = 32 * h + ((tt >> 4) << 2);   // slice col band
#pragma unroll
        for (int i2 = 0; i2 < 4; ++i2) {
          acc[i2][0] = eS[i2].x; acc[i2][1] = eS[i2].y;
          acc[i2][2] = eS[i2].z; acc[i2][3] = eS[i2].w;
        }
        for (int rr = 0; rr < KP; rr += 4) {
          float4 av[4];
#pragma unroll
          for (int i2 = 0; i2 < 4; ++i2)
            av[i2] = *(const float4*)&lds[B2_ + (r0 + i2) * 68 + rr];
#pragma unroll
          for (int k = 0; k < 4; ++k) {
            const float4 b4 = *(const float4*)&lds[SB_ + (rr + k) * 68 + c0];
#pragma unroll
            for (int i2 = 0; i2 < 4; ++i2) {
              const float a = (k == 0) ? av[i2].x : (k == 1) ? av[i2].y
                            : (k == 2) ? av[i2].z : av[i2].w;
              acc[i2][0] += a * b4.x; acc[i2][1] += a * b4.y;
              acc[i2][2] += a * b4.z; acc[i2][3] += a * b4.w;
            }
          }
        }
#pragma unroll
        for (int i2 = 0; i2 < 4; ++i2) {
          *(float4*)(E + (size_t)(k0 + r0 + i2) * NN + (sOff + c0)) =
              make_float4(acc[i2][0], acc[i2][1], acc[i2][2], acc[i2][3]);
#pragma unroll
          for (int j2 = 0; j2 < 4; ++j2)
            lds[V_ + (c0 + j2) * 65 + (r0 + i2)] = acc[i2][j2];
        }
      }
    } else if (!haveSl) {
      // diag slice: V = D (C-side) or D^T (R-side)
      for (int e = tt; e < 4096; e += 128) {
        const int a = e >> 6, b = e & 63;
        lds[V_ + a * 65 + b] = isC ? lds[D_ + a * 65 + b] : lds[D_ + b * 65 + a];
      }
    }
  }
  __syncthreads();

  // ---- s2: evolve[16,24) || micro0 (needs H[0..15]: ready s1) ----
  if (tid < 64) evolve_seg<16, 24>(lds, x, tid);
  else if (tid >= 192 && tid < 224) micro_chunk(lds, 0, tid - 192, h);
  __syncthreads();

  // ---- s3: evolve[24,32) || pgemm1 (needs V[..16) final s2, H<16 s1) ----
  if (tid < 64) evolve_seg<24, 32>(lds, x, tid);
  else if (tid < 192) pgemm_chunk(lds, 1, tid - 64, h);
  __syncthreads();

  // ---- s4: evolve[32,40) || micro1 (needs H[16..32): ready s3) ----
  if (tid < 64) evolve_seg<32, 40>(lds, x, tid);
  else if (tid >= 192 && tid < 224) micro_chunk(lds, 1, tid - 192, h);
  __syncthreads();

  // ---- s5: evolve[40,48) || pgemm2 (needs V[..32) final s4, H<32 s3) ----
  if (tid < 64) evolve_seg<40, 48>(lds, x, tid);
  else if (tid < 192) pgemm_chunk(lds, 2, tid - 64, h);
  __syncthreads();

  // ---- s6: evolve[48,56) || micro2 (needs H[32..48): ready s5) ----
  if (tid < 64) evolve_seg<48, 56>(lds, x, tid);
  else if (tid >= 192 && tid < 224) micro_chunk(lds, 2, tid - 192, h);
  __syncthreads();

  // ---- s7: evolve[56,64) || pgemm3 (needs V[..48) final s6, H<48 s5) ----
  if (tid < 64) evolve_seg<56, 64>(lds, x, tid);
  else if (tid < 192) pgemm_chunk(lds, 3, tid - 64, h);
  __syncthreads();

  // ---- s8: micro3 (needs H[48..64): ready s7) ----
  if (tid >= 192 && tid < 224) micro_chunk(lds, 3, tid - 192, h);
  __syncthreads();

  // -------- snapshot panel writeout --------
  float* Cp = Cs + (size_t)p * (NN * KP);
  float* Rp = Rs + (size_t)p * (KP * NN);
  if (isC) {
    for (int e = tid; e < 2048; e += NTHR) {
      const int a = 32 * h + (e >> 6), b = e & 63;
      Cp[(size_t)(sOff + a) * KP + b] = lds[V_ + a * 65 + b];
    }
  } else {
    for (int e = tid; e < 2048; e += NTHR) {
      const int m = e >> 5, j = 32 * h + (e & 31);
      Rp[(size_t)m * NN + (sOff + j)] = lds[V_ + j * 65 + m];
    }
  }
}

__device__ __forceinline__ float loss_elem(float Ev, float sv, float ov,
                                           float dv, float fv, int i, int j,
                                           float esc) {
  const float sp = (Ev > 0.f) ? (-0.1f * logf(Ev)) : 1e9f;
  const float ur = expf(-0.005f * sp);
  const float ub = expf(-0.01f * dv);
  const float choice = ur / (ur + ub);
  const float ug = fv * choice * (dv - 0.5f * sp);
  const float util = (ug > 0.f) ? (ug + 1.f) : expf(ug);  // elu + 1
  const float ent = sv * (((i == j) ? 1.f : 0.f) - sv);
  return sv * dv + util + esc * ent * ent + 10000.f * (sv * (1.f - ov));
}

// Final pass: E + C7*R7 (+ diag fixup C_{b-1}R_{b-1}) -> fused loss reduce.
__global__ __launch_bounds__(NTHR) void k_loss(
    const float* __restrict__ s, const float* __restrict__ o,
    const float* __restrict__ dI, const float* __restrict__ f,
    const int* __restrict__ ep, const float* __restrict__ E,
    const float* __restrict__ Cs, const float* __restrict__ Rs,
    float* __restrict__ out) {
  __shared__ float red[NTHR];
  const int tid = threadIdx.x;
  const int g = blockIdx.x * NTHR + tid;
  const int idx0 = g * 4;
  const int i = idx0 >> 9;
  const int j = idx0 & (NN - 1);
  const float* C7 = Cs + (size_t)7 * (NN * KP);
  const float* R7 = Rs + (size_t)7 * (KP * NN);
  float4 acc = *(const float4*)(E + idx0);
  {
    const float4* crow4 = (const float4*)(C7 + (size_t)i * KP);
    const float* rcol = R7 + j;
#pragma unroll 4
    for (int r4 = 0; r4 < 16; ++r4) {
      const float4 cv4 = crow4[r4];
      const float* rb = rcol + (size_t)(r4 * 4) * NN;
      float4 rv;
      rv = *(const float4*)(rb);
      acc.x += cv4.x * rv.x; acc.y += cv4.x * rv.y;
      acc.z += cv4.x * rv.z; acc.w += cv4.x * rv.w;
      rv = *(const float4*)(rb + NN);
      acc.x += cv4.y * rv.x; acc.y += cv4.y * rv.y;
      acc.z += cv4.y * rv.z; acc.w += cv4.y * rv.w;
      rv = *(const float4*)(rb + 2 * NN);
      acc.x += cv4.z * rv.x; acc.y += cv4.z * rv.y;
      acc.z += cv4.z * rv.z; acc.w += cv4.z * rv.w;
      rv = *(const float4*)(rb + 3 * NN);
      acc.x += cv4.w * rv.x; acc.y += cv4.w * rv.y;
      acc.z += cv4.w * rv.z; acc.w += cv4.w * rv.w;
    }
  }
  const int bi = i >> 6, bj = j >> 6;
  if (bi == bj && bi >= 1) {   // diag block: add the skipped C_{b-1}R_{b-1}
    const float4* cf4 = (const float4*)(Cs + (size_t)(bi - 1) * (NN * KP) + (size_t)i * KP);
    const float* rf = Rs + (size_t)(bi - 1) * (KP * NN) + j;
#pragma unroll 4
    for (int r4 = 0; r4 < 16; ++r4) {
      const float4 cv4 = cf4[r4];
      const float* rb = rf + (size_t)(r4 * 4) * NN;
      float4 rv;
      rv = *(const float4*)(rb);
      acc.x += cv4.x * rv.x; acc.y += cv4.x * rv.y;
      acc.z += cv4.x * rv.z; acc.w += cv4.x * rv.w;
      rv = *(const float4*)(rb + NN);
      acc.x += cv4.y * rv.x; acc.y += cv4.y * rv.y;
      acc.z += cv4.y * rv.z; acc.w += cv4.y * rv.w;
      rv = *(const float4*)(rb + 2 * NN);
      acc.x += cv4.z * rv.x; acc.y += cv4.z * rv.y;
      acc.z += cv4.z * rv.z; acc.w += cv4.z * rv.w;
      rv = *(const float4*)(rb + 3 * NN);
      acc.x += cv4.w * rv.x; acc.y += cv4.w * rv.y;
      acc.z += cv4.w * rv.z; acc.w += cv4.w * rv.w;
    }
  }
  const float4 sv = *(const float4*)(s + idx0);
  const float4 ov = *(const float4*)(o + idx0);
  const float4 dv = *(const float4*)(dI + idx0);
  const float4 fv = *(const float4*)(f + idx0);
  const int e = ep[0];
  const float esc = (e < 0) ? 0.f : (e < 10) ? 0.05f : (e < 50) ? 0.1f : 1.f;
  float lsum = loss_elem(acc.x, sv.x, ov.x, dv.x, fv.x, i, j + 0, esc)
             + loss_elem(acc.y, sv.y, ov.y, dv.y, fv.y, i, j + 1, esc)
             + loss_elem(acc.z, sv.z, ov.z, dv.z, fv.z, i, j + 2, esc)
             + loss_elem(acc.w, sv.w, ov.w, dv.w, fv.w, i, j + 3, esc);
  red[tid] = lsum;
  __syncthreads();
#pragma unroll
  for (int st = 128; st > 0; st >>= 1) {
    if (tid < st) red[tid] += red[tid + st];
    __syncthreads();
  }
  if (tid == 0) atomicAdd(out, red[0]);
}

extern "C" void kernel_launch(void* const* d_in, const int* in_sizes, int n_in,
                              void* d_out, int out_size, void* d_ws, size_t ws_size,
                              hipStream_t stream) {
  const float* s = (const float*)d_in[0];   // soft_adj
  const float* o = (const float*)d_in[1];   // original_adj
  const float* d = (const float*)d_in[2];   // distances
  const float* f = (const float*)d_in[3];   // flow
  const int* ep = (const int*)d_in[4];      // epoch

  float* E = (float*)d_ws;                  // 512*512
  float* Cs = E + NN * NN;                  // 8 x [512*64]
  float* Rs = Cs + NPANEL * NN * KP;        // 8 x [64*512]
  float* out = (float*)d_out;

  for (int p = 0; p < NPANEL; ++p)
    fw_phase<<<NBLK, NTHR, 0, stream>>>(s, d, E, Cs, Rs, out, p);
  k_loss<<<NBLK, NTHR, 0, stream>>>(s, o, d, f, ep, E, Cs, Rs, out);
}

// Round 8
// 215.827 us; speedup vs baseline: 1.0897x; 1.0897x over previous
//
#include <hip/hip_runtime.h>
#include <math.h>

#define NN 512
#define KP 64
#define NPANEL 8
#define NTHR 256
#define NBLK 256
#define TRUNITS (448 * 112)

// LDS float offsets (25728 floats = 100.5 KB -> 1 block/CU).
// Strides: 65 for scalar-read-by-row tiles (D,V), 68 for float4-aligned
// staged tiles (68%32=4 -> stride-4-row scalar reads land in distinct banks).
#define D_   0        // 64 x 65   diag block (state p)
#define V_   4160     // 64 x 65   V-state for substitution
#define B2_  8320     // 64 x 68   Cprev k0-rows tile
#define UB_  12672    // 64 x 68   Rprev k0-cols tile
#define SB_  17024    // 64 x 68   own-slice prev tile
#define H_   21376    // 64 x 68   evolve snapshot history
#define LDSN 25728

__device__ __forceinline__ float einit(const float* s, const float* dI, int i, int j) {
  float w = dI[i * NN + j] / (s[i * NN + j] + 1e-4f);
  if (i == j) w = 0.f;
  return expf(-10.f * w);
}

// Triangular evolve segment: pivots [M0,M1). H row m is snapshotted BEFORE
// pivot m's update; updates to rows a <= m feed nothing live downstream
// (H[a] already extracted; readlane multipliers for row a come from x[a]
// itself), so the inner loop starts at a=m+1. Bitwise-identical H.
template <int M0, int M1>
__device__ __forceinline__ void evolve_seg(float* lds, float (&x)[64], int tid) {
#pragma unroll
  for (int m = M0; m < M1; ++m) {
    const float xm = x[m];
    lds[H_ + m * 68 + tid] = xm;
#pragma unroll
    for (int a = m + 1; a < 64; ++a) {
      const int sa = __builtin_amdgcn_readlane(__float_as_int(x[a]), m);
      x[a] += __int_as_float(sa) * xm;
    }
  }
}

// Substitution partial GEMM for chunk cch (cols [16c,16c+16)): adds pivot
// contributions mp < 16c. Runs on 128 threads, tt2 in [0,128).
__device__ __forceinline__ void pgemm_chunk(float* lds, int cch, int tt2, int h) {
  const int mb = cch * 16;
  const int r = 32 * h + (tt2 & 31);
  const int g = tt2 >> 5;
  const int m0c = mb + 4 * g;
  const int vb = V_ + r * 65;
  float a0 = lds[vb + m0c + 0], a1 = lds[vb + m0c + 1];
  float a2 = lds[vb + m0c + 2], a3 = lds[vb + m0c + 3];
  for (int mp = 0; mp < mb; ++mp) {
    const float vr = lds[vb + mp];
    const float4 u4 = *(const float4*)&lds[H_ + mp * 68 + m0c];
    a0 += vr * u4.x; a1 += vr * u4.y; a2 += vr * u4.z; a3 += vr * u4.w;
  }
  lds[vb + m0c + 0] = a0; lds[vb + m0c + 1] = a1;
  lds[vb + m0c + 2] = a2; lds[vb + m0c + 3] = a3;
}

// Sequential 16x16 closure of chunk cch over this block's 32 V rows.
// t3 in [0,32).
__device__ __forceinline__ void micro_chunk(float* lds, int cch, int t3, int h) {
  const int mb = cch * 16;
  const int r = 32 * h + t3;
  const int vb = V_ + r * 65 + mb;
  float v[16];
#pragma unroll
  for (int u2 = 0; u2 < 16; ++u2) v[u2] = lds[vb + u2];
#pragma unroll
  for (int mp = 0; mp < 15; ++mp) {
    const float vmp = v[mp];
#pragma unroll
    for (int m2 = mp + 1; m2 < 16; ++m2)
      v[m2] += vmp * lds[H_ + (mb + mp) * 68 + (mb + m2)];
  }
#pragma unroll
  for (int u2 = 0; u2 < 16; ++u2) lds[vb + u2] = v[u2];
}

// Phase p (one launch per phase; inter-launch barrier = phase sync):
//  blocks 0..31  : panel blocks. Prefetch E reads (diag+slice) to regs,
//    stage prev C/R tiles, diag GEMM, then a 4-slot pipeline: evolve
//    segment k (wave 0, triangular, barrier-free within a slot) runs
//    CONCURRENT with slice GEMM / substitution pieces on waves 1-3.
//    (4 equal 16-pivot segments beat both coarser and finer splits:
//     R7's 8-slot variant regressed +19us -- short evolve segments
//     stall at barriers against the serial micro chunks.)
//  blocks 32..255: trailing rank-64 update of complement(cross(p)) (p>0),
//    or E init there (p==0).
// Diag block (p,p) never written in-phase; diag b misses exactly
// C_{b-1}R_{b-1}, fixed in k_loss (which also adds C_7R_7).
__global__ __launch_bounds__(NTHR) void fw_phase(
    const float* __restrict__ s, const float* __restrict__ dI,
    float* __restrict__ E, float* __restrict__ Cs, float* __restrict__ Rs,
    float* __restrict__ out, int p) {
  __shared__ __align__(16) float lds[LDSN];
  const int blk = blockIdx.x, tid = threadIdx.x;
  const int k0 = p * KP;

  if (blk >= 32) {
    // ================= trailing blocks =================
    const int gt = (blk - 32) * NTHR + tid;
    if (p == 0) {
      if (blk == 32 && tid == 0) out[0] = 0.f;   // zero loss accumulator
      if (gt < TRUNITS) {
        const int ii = gt / 112;
        const int jj = gt - ii * 112;
        const int i = ii + KP;
        const int j = (jj + 16) << 2;
        const int idx = i * NN + j;
        const float4 sv = *(const float4*)(s + idx);
        const float4 dv = *(const float4*)(dI + idx);
        float w0 = dv.x / (sv.x + 1e-4f); if (i == j + 0) w0 = 0.f;
        float w1 = dv.y / (sv.y + 1e-4f); if (i == j + 1) w1 = 0.f;
        float w2 = dv.z / (sv.z + 1e-4f); if (i == j + 2) w2 = 0.f;
        float w3 = dv.w / (sv.w + 1e-4f); if (i == j + 3) w3 = 0.f;
        *(float4*)(E + idx) = make_float4(expf(-10.f * w0), expf(-10.f * w1),
                                          expf(-10.f * w2), expf(-10.f * w3));
      }
    } else if (gt < TRUNITS) {
      const int ii = gt / 112;
      const int jj = gt - ii * 112;
      const int i = (ii < k0) ? ii : ii + KP;
      const int j = ((jj < (p << 4)) ? jj : jj + 16) << 2;
      const int idx = i * NN + j;
      const float* Cprev = Cs + (size_t)(p - 1) * (NN * KP);
      const float* Rprev = Rs + (size_t)(p - 1) * (KP * NN);
      float4 acc = *(const float4*)(E + idx);
      const float4* crow4 = (const float4*)(Cprev + (size_t)i * KP);
      const float* rcol = Rprev + j;
#pragma unroll 4
      for (int r4 = 0; r4 < 16; ++r4) {
        const float4 cv4 = crow4[r4];
        const float* rb = rcol + (size_t)(r4 * 4) * NN;
        float4 rv;
        rv = *(const float4*)(rb);
        acc.x += cv4.x * rv.x; acc.y += cv4.x * rv.y;
        acc.z += cv4.x * rv.z; acc.w += cv4.x * rv.w;
        rv = *(const float4*)(rb + NN);
        acc.x += cv4.y * rv.x; acc.y += cv4.y * rv.y;
        acc.z += cv4.y * rv.z; acc.w += cv4.y * rv.w;
        rv = *(const float4*)(rb + 2 * NN);
        acc.x += cv4.z * rv.x; acc.y += cv4.z * rv.y;
        acc.z += cv4.z * rv.z; acc.w += cv4.z * rv.w;
        rv = *(const float4*)(rb + 3 * NN);
        acc.x += cv4.w * rv.x; acc.y += cv4.w * rv.y;
        acc.z += cv4.w * rv.z; acc.w += cv4.w * rv.w;
      }
      *(float4*)(E + idx) = acc;
    }
    return;
  }

  // ================= panel blocks =================
  const bool isC = (blk < 16);
  const int sb = (blk >> 1) & 7;
  const int h = blk & 1;                 // half: rows/cols [32h, 32h+32)
  const int sOff = sb * KP;
  const bool haveSl = (sb != p);
  const float* Cprev = Cs + (size_t)(p - 1) * (NN * KP);
  const float* Rprev = Rs + (size_t)(p - 1) * (KP * NN);

  // prefetched E fragments (loaded in p>0 path before the staging barrier;
  // consumed by diag GEMM / slice GEMM). Race-free: diag(p) is not written
  // in-phase by anyone; the slice region is written only by THIS block.
  float4 eS[4];

  if (p == 0) {
    // direct init of diag + own slice; write E (blk0 owns diag region)
    for (int e = tid; e < 4096; e += NTHR) {
      const int a = e >> 6, b = e & 63;
      const float v = einit(s, dI, a, b);
      lds[D_ + a * 65 + b] = v;
      if (blk == 0) E[a * NN + b] = v;
    }
    if (haveSl) {
      if (isC) {
        for (int e = tid; e < 2048; e += NTHR) {
          const int a = 32 * h + (e >> 6), b = e & 63;
          const float v = einit(s, dI, sOff + a, b);
          lds[V_ + a * 65 + b] = v;
          E[(sOff + a) * NN + b] = v;
        }
      } else {
        for (int e = tid; e < 2048; e += NTHR) {
          const int m = e >> 5, j = 32 * h + (e & 31);
          const float v = einit(s, dI, m, sOff + j);
          lds[V_ + j * 65 + m] = v;
          E[m * NN + (sOff + j)] = v;
        }
      }
    }
  } else {
    // -------- prefetch E reads (overlap with staging latency) --------
    float4 eD[4];
    {
      const int r0 = (tid >> 4) << 2, m0 = (tid & 15) << 2;
#pragma unroll
      for (int i2 = 0; i2 < 4; ++i2)
        eD[i2] = *(const float4*)(E + (size_t)(k0 + r0 + i2) * NN + (k0 + m0));
    }
    if (haveSl && tid >= 64 && tid < 192) {
      const int tt = tid - 64;
      if (isC) {
        const int r0 = 32 * h + ((tt >> 4) << 2);
        const int m0 = (tt & 15) << 2;
#pragma unroll
        for (int i2 = 0; i2 < 4; ++i2)
          eS[i2] = *(const float4*)(E + (size_t)(sOff + r0 + i2) * NN + (k0 + m0));
      } else {
        const int r0 = (tt & 15) << 2;
        const int c0 = 32 * h + ((tt >> 4) << 2);
#pragma unroll
        for (int i2 = 0; i2 < 4; ++i2)
          eS[i2] = *(const float4*)(E + (size_t)(k0 + r0 + i2) * NN + (sOff + c0));
      }
    }
    // -------- stage tiles (float4, stride-68) --------
#pragma unroll
    for (int k = 0; k < 4; ++k) {
      const int e4 = tid + k * NTHR;
      const int a = e4 >> 4, b4 = (e4 & 15) << 2;
      *(float4*)&lds[B2_ + a * 68 + b4] =
          *(const float4*)(Cprev + (size_t)(k0 + a) * KP + b4);
      *(float4*)&lds[UB_ + a * 68 + b4] =
          *(const float4*)(Rprev + (size_t)a * NN + (k0 + b4));
      if (haveSl) {
        if (isC)
          *(float4*)&lds[SB_ + a * 68 + b4] =
              *(const float4*)(Cprev + (size_t)(sOff + a) * KP + b4);
        else
          *(float4*)&lds[SB_ + a * 68 + b4] =
              *(const float4*)(Rprev + (size_t)a * NN + (sOff + b4));
      }
    }
    __syncthreads();
    // -------- diag GEMM: D = E[diag] + Ck0 * Rk0 (state p) --------
    {
      const int r0 = (tid >> 4) << 2, m0 = (tid & 15) << 2;
      float acc[4][4];
#pragma unroll
      for (int i2 = 0; i2 < 4; ++i2) {
        acc[i2][0] = eD[i2].x; acc[i2][1] = eD[i2].y;
        acc[i2][2] = eD[i2].z; acc[i2][3] = eD[i2].w;
      }
      for (int rr = 0; rr < KP; rr += 4) {
        float4 av[4];
#pragma unroll
        for (int i2 = 0; i2 < 4; ++i2)
          av[i2] = *(const float4*)&lds[B2_ + (r0 + i2) * 68 + rr];
#pragma unroll
        for (int k = 0; k < 4; ++k) {
          const float4 b4 = *(const float4*)&lds[UB_ + (rr + k) * 68 + m0];
#pragma unroll
          for (int i2 = 0; i2 < 4; ++i2) {
            const float a = (k == 0) ? av[i2].x : (k == 1) ? av[i2].y
                          : (k == 2) ? av[i2].z : av[i2].w;
            acc[i2][0] += a * b4.x; acc[i2][1] += a * b4.y;
            acc[i2][2] += a * b4.z; acc[i2][3] += a * b4.w;
          }
        }
      }
#pragma unroll
      for (int i2 = 0; i2 < 4; ++i2)
#pragma unroll
        for (int j2 = 0; j2 < 4; ++j2)
          lds[D_ + (r0 + i2) * 65 + (m0 + j2)] = acc[i2][j2];
    }
  }
  __syncthreads();

  // ======== pipelined region: wave0 evolve segments || waves1-3 work ========
  float x[64];
  // ---- slot 1: evolve[0,16) || slice GEMM / diag-slice copy ----
  if (tid < 64) {
    if (isC) {
#pragma unroll
      for (int a = 0; a < 64; ++a) x[a] = lds[D_ + a * 65 + tid];
    } else {
#pragma unroll
      for (int a = 0; a < 64; ++a) x[a] = lds[D_ + tid * 65 + a];
    }
    evolve_seg<0, 16>(lds, x, tid);
  } else if (tid < 192) {
    const int tt = tid - 64;
    if (haveSl && p > 0) {
      // slice GEMM: V = E[slice] + prev rank-64; write corrected E back
      float acc[4][4];
      if (isC) {
        const int r0 = 32 * h + ((tt >> 4) << 2);
        const int m0 = (tt & 15) << 2;
#pragma unroll
        for (int i2 = 0; i2 < 4; ++i2) {
          acc[i2][0] = eS[i2].x; acc[i2][1] = eS[i2].y;
          acc[i2][2] = eS[i2].z; acc[i2][3] = eS[i2].w;
        }
        for (int rr = 0; rr < KP; rr += 4) {
          float4 av[4];
#pragma unroll
          for (int i2 = 0; i2 < 4; ++i2)
            av[i2] = *(const float4*)&lds[SB_ + (r0 + i2) * 68 + rr];
#pragma unroll
          for (int k = 0; k < 4; ++k) {
            const float4 b4 = *(const float4*)&lds[UB_ + (rr + k) * 68 + m0];
#pragma unroll
            for (int i2 = 0; i2 < 4; ++i2) {
              const float a = (k == 0) ? av[i2].x : (k == 1) ? av[i2].y
                            : (k == 2) ? av[i2].z : av[i2].w;
              acc[i2][0] += a * b4.x; acc[i2][1] += a * b4.y;
              acc[i2][2] += a * b4.z; acc[i2][3] += a * b4.w;
            }
          }
        }
#pragma unroll
        for (int i2 = 0; i2 < 4; ++i2) {
          *(float4*)(E + (size_t)(sOff + r0 + i2) * NN + (k0 + m0)) =
              make_float4(acc[i2][0], acc[i2][1], acc[i2][2], acc[i2][3]);
#pragma unroll
          for (int j2 = 0; j2 < 4; ++j2)
            lds[V_ + (r0 + i2) * 65 + (m0 + j2)] = acc[i2][j2];
        }
      } else {
        const int r0 = (tt & 15) << 2;              // m rows k0+r0..
        const int c0 = 32 * h + ((tt >> 4) << 2);   // slice col band
#pragma unroll
        for (int i2 = 0; i2 < 4; ++i2) {
          acc[i2][0] = eS[i2].x; acc[i2][1] = eS[i2].y;
          acc[i2][2] = eS[i2].z; acc[i2][3] = eS[i2].w;
        }
        for (int rr = 0; rr < KP; rr += 4) {
          float4 av[4];
#pragma unroll
          for (int i2 = 0; i2 < 4; ++i2)
            av[i2] = *(const float4*)&lds[B2_ + (r0 + i2) * 68 + rr];
#pragma unroll
          for (int k = 0; k < 4; ++k) {
            const float4 b4 = *(const float4*)&lds[SB_ + (rr + k) * 68 + c0];
#pragma unroll
            for (int i2 = 0; i2 < 4; ++i2) {
              const float a = (k == 0) ? av[i2].x : (k == 1) ? av[i2].y
                            : (k == 2) ? av[i2].z : av[i2].w;
              acc[i2][0] += a * b4.x; acc[i2][1] += a * b4.y;
              acc[i2][2] += a * b4.z; acc[i2][3] += a * b4.w;
            }
          }
        }
#pragma unroll
        for (int i2 = 0; i2 < 4; ++i2) {
          *(float4*)(E + (size_t)(k0 + r0 + i2) * NN + (sOff + c0)) =
              make_float4(acc[i2][0], acc[i2][1], acc[i2][2], acc[i2][3]);
#pragma unroll
          for (int j2 = 0; j2 < 4; ++j2)
            lds[V_ + (c0 + j2) * 65 + (r0 + i2)] = acc[i2][j2];
        }
      }
    } else if (!haveSl) {
      // diag slice: V = D (C-side) or D^T (R-side)
      for (int e = tt; e < 4096; e += 128) {
        const int a = e >> 6, b = e & 63;
        lds[V_ + a * 65 + b] = isC ? lds[D_ + a * 65 + b] : lds[D_ + b * 65 + a];
      }
    }
  }
  __syncthreads();

  // ---- slot 2: evolve[16,32) || micro chunk0 (needs H[0..15]) ----
  if (tid < 64) evolve_seg<16, 32>(lds, x, tid);
  else if (tid >= 192 && tid < 224) micro_chunk(lds, 0, tid - 192, h);
  __syncthreads();

  // ---- slot 3: evolve[32,48) || pGEMM chunk1 (needs H[0..15], V[0..15]) ----
  if (tid < 64) evolve_seg<32, 48>(lds, x, tid);
  else if (tid < 192) pgemm_chunk(lds, 1, tid - 64, h);
  __syncthreads();

  // ---- slot 4: evolve[48,64) || micro chunk1 (needs H[16..31]) ----
  if (tid < 64) evolve_seg<48, 64>(lds, x, tid);
  else if (tid >= 192 && tid < 224) micro_chunk(lds, 1, tid - 192, h);
  __syncthreads();

  // ---- serial tail of the substitution chain ----
  if (tid >= 64 && tid < 192) pgemm_chunk(lds, 2, tid - 64, h);
  __syncthreads();
  if (tid >= 192 && tid < 224) micro_chunk(lds, 2, tid - 192, h);
  __syncthreads();
  if (tid >= 64 && tid < 192) pgemm_chunk(lds, 3, tid - 64, h);
  __syncthreads();
  if (tid >= 192 && tid < 224) micro_chunk(lds, 3, tid - 192, h);
  __syncthreads();

  // -------- snapshot panel writeout --------
  float* Cp = Cs + (size_t)p * (NN * KP);
  float* Rp = Rs + (size_t)p * (KP * NN);
  if (isC) {
    for (int e = tid; e < 2048; e += NTHR) {
      const int a = 32 * h + (e >> 6), b = e & 63;
      Cp[(size_t)(sOff + a) * KP + b] = lds[V_ + a * 65 + b];
    }
  } else {
    for (int e = tid; e < 2048; e += NTHR) {
      const int m = e >> 5, j = 32 * h + (e & 31);
      Rp[(size_t)m * NN + (sOff + j)] = lds[V_ + j * 65 + m];
    }
  }
}

__device__ __forceinline__ float loss_elem(float Ev, float sv, float ov,
                                           float dv, float fv, int i, int j,
                                           float esc) {
  const float sp = (Ev > 0.f) ? (-0.1f * logf(Ev)) : 1e9f;
  const float ur = expf(-0.005f * sp);
  const float ub = expf(-0.01f * dv);
  const float choice = ur / (ur + ub);
  const float ug = fv * choice * (dv - 0.5f * sp);
  const float util = (ug > 0.f) ? (ug + 1.f) : expf(ug);  // elu + 1
  const float ent = sv * (((i == j) ? 1.f : 0.f) - sv);
  return sv * dv + util + esc * ent * ent + 10000.f * (sv * (1.f - ov));
}

// Final pass: E + C7*R7 (+ diag fixup C_{b-1}R_{b-1}) -> fused loss reduce.
__global__ __launch_bounds__(NTHR) void k_loss(
    const float* __restrict__ s, const float* __restrict__ o,
    const float* __restrict__ dI, const float* __restrict__ f,
    const int* __restrict__ ep, const float* __restrict__ E,
    const float* __restrict__ Cs, const float* __restrict__ Rs,
    float* __restrict__ out) {
  __shared__ float red[NTHR];
  const int tid = threadIdx.x;
  const int g = blockIdx.x * NTHR + tid;
  const int idx0 = g * 4;
  const int i = idx0 >> 9;
  const int j = idx0 & (NN - 1);
  const float* C7 = Cs + (size_t)7 * (NN * KP);
  const float* R7 = Rs + (size_t)7 * (KP * NN);
  float4 acc = *(const float4*)(E + idx0);
  {
    const float4* crow4 = (const float4*)(C7 + (size_t)i * KP);
    const float* rcol = R7 + j;
#pragma unroll 4
    for (int r4 = 0; r4 < 16; ++r4) {
      const float4 cv4 = crow4[r4];
      const float* rb = rcol + (size_t)(r4 * 4) * NN;
      float4 rv;
      rv = *(const float4*)(rb);
      acc.x += cv4.x * rv.x; acc.y += cv4.x * rv.y;
      acc.z += cv4.x * rv.z; acc.w += cv4.x * rv.w;
      rv = *(const float4*)(rb + NN);
      acc.x += cv4.y * rv.x; acc.y += cv4.y * rv.y;
      acc.z += cv4.y * rv.z; acc.w += cv4.y * rv.w;
      rv = *(const float4*)(rb + 2 * NN);
      acc.x += cv4.z * rv.x; acc.y += cv4.z * rv.y;
      acc.z += cv4.z * rv.z; acc.w += cv4.z * rv.w;
      rv = *(const float4*)(rb + 3 * NN);
      acc.x += cv4.w * rv.x; acc.y += cv4.w * rv.y;
      acc.z += cv4.w * rv.z; acc.w += cv4.w * rv.w;
    }
  }
  const int bi = i >> 6, bj = j >> 6;
  if (bi == bj && bi >= 1) {   // diag block: add the skipped C_{b-1}R_{b-1}
    const float4* cf4 = (const float4*)(Cs + (size_t)(bi - 1) * (NN * KP) + (size_t)i * KP);
    const float* rf = Rs + (size_t)(bi - 1) * (KP * NN) + j;
#pragma unroll 4
    for (int r4 = 0; r4 < 16; ++r4) {
      const float4 cv4 = cf4[r4];
      const float* rb = rf + (size_t)(r4 * 4) * NN;
      float4 rv;
      rv = *(const float4*)(rb);
      acc.x += cv4.x * rv.x; acc.y += cv4.x * rv.y;
      acc.z += cv4.x * rv.z; acc.w += cv4.x * rv.w;
      rv = *(const float4*)(rb + NN);
      acc.x += cv4.y * rv.x; acc.y += cv4.y * rv.y;
      acc.z += cv4.y * rv.z; acc.w += cv4.y * rv.w;
      rv = *(const float4*)(rb + 2 * NN);
      acc.x += cv4.z * rv.x; acc.y += cv4.z * rv.y;
      acc.z += cv4.z * rv.z; acc.w += cv4.z * rv.w;
      rv = *(const float4*)(rb + 3 * NN);
      acc.x += cv4.w * rv.x; acc.y += cv4.w * rv.y;
      acc.z += cv4.w * rv.z; acc.w += cv4.w * rv.w;
    }
  }
  const float4 sv = *(const float4*)(s + idx0);
  const float4 ov = *(const float4*)(o + idx0);
  const float4 dv = *(const float4*)(dI + idx0);
  const float4 fv = *(const float4*)(f + idx0);
  const int e = ep[0];
  const float esc = (e < 0) ? 0.f : (e < 10) ? 0.05f : (e < 50) ? 0.1f : 1.f;
  float lsum = loss_elem(acc.x, sv.x, ov.x, dv.x, fv.x, i, j + 0, esc)
             + loss_elem(acc.y, sv.y, ov.y, dv.y, fv.y, i, j + 1, esc)
             + loss_elem(acc.z, sv.z, ov.z, dv.z, fv.z, i, j + 2, esc)
             + loss_elem(acc.w, sv.w, ov.w, dv.w, fv.w, i, j + 3, esc);
  red[tid] = lsum;
  __syncthreads();
#pragma unroll
  for (int st = 128; st > 0; st >>= 1) {
    if (tid < st) red[tid] += red[tid + st];
    __syncthreads();
  }
  if (tid == 0) atomicAdd(out, red[0]);
}

extern "C" void kernel_launch(void* const* d_in, const int* in_sizes, int n_in,
                              void* d_out, int out_size, void* d_ws, size_t ws_size,
                              hipStream_t stream) {
  const float* s = (const float*)d_in[0];   // soft_adj
  const float* o = (const float*)d_in[1];   // original_adj
  const float* d = (const float*)d_in[2];   // distances
  const float* f = (const float*)d_in[3];   // flow
  const int* ep = (const int*)d_in[4];      // epoch

  float* E = (float*)d_ws;                  // 512*512
  float* Cs = E + NN * NN;                  // 8 x [512*64]
  float* Rs = Cs + NPANEL * NN * KP;        // 8 x [64*512]
  float* out = (float*)d_out;

  for (int p = 0; p < NPANEL; ++p)
    fw_phase<<<NBLK, NTHR, 0, stream>>>(s, d, E, Cs, Rs, out, p);
  k_loss<<<NBLK, NTHR, 0, stream>>>(s, o, d, f, ep, E, Cs, Rs, out);
}